// Round 2
// baseline (634.985 us; speedup 1.0000x reference)
//
#include <hip/hip_runtime.h>
#include <hip/hip_bf16.h>

typedef float f32x4 __attribute__((ext_vector_type(4)));
typedef short bf16x8 __attribute__((ext_vector_type(8)));
typedef unsigned short ushort;

#define BM 128
#define BN 128
#define BK 32

// ---------- helpers ----------

__device__ inline ushort f2bf(float f) {
    __hip_bfloat16 h = __float2bfloat16(f);   // RNE
    ushort s;
    __builtin_memcpy(&s, &h, 2);
    return s;
}

__device__ inline bf16x8 quant_pack8(float4 a, float4 b, float inv_scale, float zp) {
    float v[8] = {a.x, a.y, a.z, a.w, b.x, b.y, b.z, b.w};
    union { bf16x8 v8; ushort s[8]; } o;
#pragma unroll
    for (int j = 0; j < 8; ++j) {
        float t = rintf(fmaf(v[j], inv_scale, zp));
        t = fminf(127.0f, fmaxf(-128.0f, t));
        o.s[j] = f2bf(t);
    }
    return o.v8;
}

__device__ inline bf16x8 cvt_pack8(float4 a, float4 b) {
    float v[8] = {a.x, a.y, a.z, a.w, b.x, b.y, b.z, b.w};
    union { bf16x8 v8; ushort s[8]; } o;
#pragma unroll
    for (int j = 0; j < 8; ++j) o.s[j] = f2bf(v[j]);
    return o.v8;
}

#define GLL16(gp, lp)                                                              \
    __builtin_amdgcn_global_load_lds(                                              \
        (const __attribute__((address_space(1))) unsigned int*)(gp),               \
        (__attribute__((address_space(3))) unsigned int*)(lp), 16, 0, 0)

// ---------- kernel 1: per-block min/max partials ----------

__global__ __launch_bounds__(256) void minmax_partial(const float* __restrict__ x, int n4,
                                                      float* __restrict__ pmin,
                                                      float* __restrict__ pmax) {
    float lmin = 3.4e38f, lmax = -3.4e38f;
    const float4* xv = (const float4*)x;
    int stride = gridDim.x * blockDim.x;
    for (int i = blockIdx.x * blockDim.x + threadIdx.x; i < n4; i += stride) {
        float4 v = xv[i];
        lmin = fminf(lmin, fminf(fminf(v.x, v.y), fminf(v.z, v.w)));
        lmax = fmaxf(lmax, fmaxf(fmaxf(v.x, v.y), fmaxf(v.z, v.w)));
    }
#pragma unroll
    for (int off = 32; off > 0; off >>= 1) {
        lmin = fminf(lmin, __shfl_down(lmin, off));
        lmax = fmaxf(lmax, __shfl_down(lmax, off));
    }
    __shared__ float smin[4], smax[4];
    int w = threadIdx.x >> 6;
    if ((threadIdx.x & 63) == 0) { smin[w] = lmin; smax[w] = lmax; }
    __syncthreads();
    if (threadIdx.x == 0) {
        pmin[blockIdx.x] = fminf(fminf(smin[0], smin[1]), fminf(smin[2], smin[3]));
        pmax[blockIdx.x] = fmaxf(fmaxf(smax[0], smax[1]), fmaxf(smax[2], smax[3]));
    }
}

// ---------- kernel 2: finalize scale/zp ----------

__global__ __launch_bounds__(64) void finalize_qp(const float* __restrict__ pmin,
                                                  const float* __restrict__ pmax, int nb,
                                                  float* __restrict__ hdr) {
    float lmin = 3.4e38f, lmax = -3.4e38f;
    for (int i = threadIdx.x; i < nb; i += 64) {
        lmin = fminf(lmin, pmin[i]);
        lmax = fmaxf(lmax, pmax[i]);
    }
#pragma unroll
    for (int off = 32; off > 0; off >>= 1) {
        lmin = fminf(lmin, __shfl_down(lmin, off));
        lmax = fmaxf(lmax, __shfl_down(lmax, off));
    }
    if (threadIdx.x == 0) {
        float scale = (lmax - lmin) / 255.0f;
        float zp = -128.0f - rintf(lmin / scale);
        zp = fminf(127.0f, fmaxf(-128.0f, zp));
        hdr[0] = 1.0f / scale;
        hdr[1] = zp;
    }
}

// ---------- kernel 3a: quantize x -> bf16 codes ----------

__global__ __launch_bounds__(256) void quant_x_kernel(const float* __restrict__ x,
                                                      ushort* __restrict__ xq,
                                                      const float* __restrict__ qp, int n8) {
    const float inv_scale = qp[0];
    const float zp = qp[1];
    int stride = gridDim.x * blockDim.x;
    for (int i = blockIdx.x * blockDim.x + threadIdx.x; i < n8; i += stride) {
        float4 a = *(const float4*)(x + (size_t)i * 8);
        float4 b = *(const float4*)(x + (size_t)i * 8 + 4);
        *(bf16x8*)(xq + (size_t)i * 8) = quant_pack8(a, b, inv_scale, zp);
    }
}

// ---------- kernel 3b: convert W -> bf16 ----------

__global__ __launch_bounds__(256) void cvt_w_kernel(const float* __restrict__ w,
                                                    ushort* __restrict__ wq, int n8) {
    int stride = gridDim.x * blockDim.x;
    for (int i = blockIdx.x * blockDim.x + threadIdx.x; i < n8; i += stride) {
        float4 a = *(const float4*)(w + (size_t)i * 8);
        float4 b = *(const float4*)(w + (size_t)i * 8 + 4);
        *(bf16x8*)(wq + (size_t)i * 8) = cvt_pack8(a, b);
    }
}

// ---------- kernel 4: bf16 MFMA GEMM (m97 structure: global_load_lds w16) ----------
// C = A(MxK) * B(NxK)^T + bias. A,B pre-converted bf16.

__global__ __launch_bounds__(256) void gemm_bt(const ushort* __restrict__ A,
                                               const ushort* __restrict__ Bw,
                                               const float* __restrict__ bias,
                                               float* __restrict__ out,
                                               int M, int N, int K) {
    // LDS flat layout: chunk c (16B) = k-group g = c>>7, row = c&127.
    __shared__ ushort As[4][BM][8];  // 8 KB
    __shared__ ushort Bs[4][BN][8];  // 8 KB

    const int tid = threadIdx.x;
    const int lane = tid & 63;
    const int wid = tid >> 6;

    // bijective XCD swizzle (gridDim.x % 8 == 0 here: 2048)
    const int nwg = gridDim.x;
    const int cpx = nwg >> 3;
    const int swz = (blockIdx.x & 7) * cpx + (blockIdx.x >> 3);
    const int nbn = N / BN;
    const int bm = (swz / nbn) * BM;
    const int bn = (swz % nbn) * BN;

    const int wm = (wid >> 1) * 64;
    const int wn = (wid & 1) * 64;
    const int l16 = lane & 15;
    const int kg = lane >> 4;

    // staging chunks: call0 -> chunk tid, call1 -> chunk tid+256
    const int c0 = tid, c1 = tid + 256;
    const int r0 = c0 & 127, g0 = c0 >> 7;
    const int r1 = c1 & 127, g1 = c1 >> 7;

    const ushort* a0 = A + (size_t)(bm + r0) * K + g0 * 8;
    const ushort* a1 = A + (size_t)(bm + r1) * K + g1 * 8;
    const ushort* b0 = Bw + (size_t)(bn + r0) * K + g0 * 8;
    const ushort* b1 = Bw + (size_t)(bn + r1) * K + g1 * 8;

    ushort* As_flat = &As[0][0][0];
    ushort* Bs_flat = &Bs[0][0][0];
    ushort* dstA0 = As_flat + (size_t)(wid * 64) * 8;
    ushort* dstA1 = As_flat + (size_t)(wid * 64 + 256) * 8;
    ushort* dstB0 = Bs_flat + (size_t)(wid * 64) * 8;
    ushort* dstB1 = Bs_flat + (size_t)(wid * 64 + 256) * 8;

    f32x4 acc[4][4];
#pragma unroll
    for (int i = 0; i < 4; ++i)
#pragma unroll
        for (int j = 0; j < 4; ++j) acc[i][j] = (f32x4){0.f, 0.f, 0.f, 0.f};

    const int nk = K / BK;
    for (int kt = 0; kt < nk; ++kt) {
        GLL16(a0, dstA0);
        GLL16(a1, dstA1);
        GLL16(b0, dstB0);
        GLL16(b1, dstB1);
        a0 += BK; a1 += BK; b0 += BK; b1 += BK;

        __syncthreads();   // drains vmcnt(0): tile fully in LDS for all waves

        bf16x8 af[4], bfr[4];
#pragma unroll
        for (int i = 0; i < 4; ++i)
            af[i] = *(const bf16x8*)&As[kg][wm + i * 16 + l16][0];
#pragma unroll
        for (int j = 0; j < 4; ++j)
            bfr[j] = *(const bf16x8*)&Bs[kg][wn + j * 16 + l16][0];

#pragma unroll
        for (int i = 0; i < 4; ++i)
#pragma unroll
            for (int j = 0; j < 4; ++j)
                acc[i][j] = __builtin_amdgcn_mfma_f32_16x16x32_bf16(af[i], bfr[j], acc[i][j], 0, 0, 0);

        __syncthreads();   // all reads done before next stage overwrites
    }

    // epilogue: C/D layout col = lane&15, row = (lane>>4)*4 + r
#pragma unroll
    for (int j = 0; j < 4; ++j) {
        const int col = bn + wn + j * 16 + l16;
        const float bj = bias[col];
#pragma unroll
        for (int i = 0; i < 4; ++i) {
            const int rowb = bm + wm + i * 16 + kg * 4;
            float* po = out + (size_t)rowb * N + col;
#pragma unroll
            for (int r = 0; r < 4; ++r) po[(size_t)r * N] = acc[i][j][r] + bj;
        }
    }
}

// ---------- fallback: fused quantize+GEMM (round-1 kernel, used if ws too small) ----------

__global__ __launch_bounds__(256) void qgemm_fused(const float* __restrict__ x,
                                                   const float* __restrict__ w,
                                                   const float* __restrict__ bias,
                                                   const float* __restrict__ qp,
                                                   float* __restrict__ out,
                                                   int M, int N, int K) {
    __shared__ ushort As[4][BM][8];
    __shared__ ushort Bs[4][BN][8];

    const int tid = threadIdx.x;
    const int bm = blockIdx.y * BM;
    const int bn = blockIdx.x * BN;
    const float inv_scale = qp[0];
    const float zp = qp[1];
    const int lane = tid & 63;
    const int wid = tid >> 6;
    const int wm = (wid >> 1) * 64;
    const int wn = (wid & 1) * 64;
    const int l16 = lane & 15;
    const int kg = lane >> 4;
    const int r0 = tid >> 2;
    const int g0 = tid & 3;

    const float* pa0 = x + (size_t)(bm + r0) * K + g0 * 8;
    const float* pa1 = pa0 + (size_t)64 * K;
    const float* pb0 = w + (size_t)(bn + r0) * K + g0 * 8;
    const float* pb1 = pb0 + (size_t)64 * K;

    f32x4 acc[4][4];
#pragma unroll
    for (int i = 0; i < 4; ++i)
#pragma unroll
        for (int j = 0; j < 4; ++j) acc[i][j] = (f32x4){0.f, 0.f, 0.f, 0.f};

    const int nk = K / BK;
    for (int kt = 0; kt < nk; ++kt) {
        float4 a00 = *(const float4*)(pa0 + 0);
        float4 a01 = *(const float4*)(pa0 + 4);
        float4 a10 = *(const float4*)(pa1 + 0);
        float4 a11 = *(const float4*)(pa1 + 4);
        float4 b00 = *(const float4*)(pb0 + 0);
        float4 b01 = *(const float4*)(pb0 + 4);
        float4 b10 = *(const float4*)(pb1 + 0);
        float4 b11 = *(const float4*)(pb1 + 4);
        pa0 += BK; pa1 += BK; pb0 += BK; pb1 += BK;

        bf16x8 qa0 = quant_pack8(a00, a01, inv_scale, zp);
        bf16x8 qa1 = quant_pack8(a10, a11, inv_scale, zp);
        bf16x8 wb0 = cvt_pack8(b00, b01);
        bf16x8 wb1 = cvt_pack8(b10, b11);

        __syncthreads();
        *(bf16x8*)&As[g0][r0][0]      = qa0;
        *(bf16x8*)&As[g0][r0 + 64][0] = qa1;
        *(bf16x8*)&Bs[g0][r0][0]      = wb0;
        *(bf16x8*)&Bs[g0][r0 + 64][0] = wb1;
        __syncthreads();

        bf16x8 af[4], bfr[4];
#pragma unroll
        for (int i = 0; i < 4; ++i)
            af[i] = *(const bf16x8*)&As[kg][wm + i * 16 + l16][0];
#pragma unroll
        for (int j = 0; j < 4; ++j)
            bfr[j] = *(const bf16x8*)&Bs[kg][wn + j * 16 + l16][0];
#pragma unroll
        for (int i = 0; i < 4; ++i)
#pragma unroll
            for (int j = 0; j < 4; ++j)
                acc[i][j] = __builtin_amdgcn_mfma_f32_16x16x32_bf16(af[i], bfr[j], acc[i][j], 0, 0, 0);
    }

#pragma unroll
    for (int j = 0; j < 4; ++j) {
        const int col = bn + wn + j * 16 + l16;
        const float bj = bias[col];
#pragma unroll
        for (int i = 0; i < 4; ++i) {
            const int rowb = bm + wm + i * 16 + kg * 4;
            float* po = out + (size_t)rowb * N + col;
#pragma unroll
            for (int r = 0; r < 4; ++r) po[(size_t)r * N] = acc[i][j][r] + bj;
        }
    }
}

// ---------- launch ----------

extern "C" void kernel_launch(void* const* d_in, const int* in_sizes, int n_in,
                              void* d_out, int out_size, void* d_ws, size_t ws_size,
                              hipStream_t stream) {
    const float* x    = (const float*)d_in[0];
    const float* w    = (const float*)d_in[1];
    const float* bias = (const float*)d_in[2];
    float* out = (float*)d_out;
    char* ws = (char*)d_ws;

    const int N = in_sizes[2];            // 4096
    const int K = in_sizes[1] / N;        // 4096
    const int M = in_sizes[0] / K;        // 8192

    // ws layout (bytes): hdr@0 (64B), pmin@4096 (4KB), pmax@8192 (4KB),
    // xq@16384 (M*K*2), wq after.
    const size_t xq_off = 16384;
    const size_t xq_bytes = (size_t)M * K * 2;
    const size_t wq_off = xq_off + xq_bytes;
    const size_t wq_bytes = (size_t)N * K * 2;
    const size_t need = wq_off + wq_bytes;

    float* hdr  = (float*)ws;
    float* pmin = (float*)(ws + 4096);
    float* pmax = (float*)(ws + 8192);

    const int n4 = in_sizes[0] / 4;

    if (ws_size >= need) {
        ushort* xq = (ushort*)(ws + xq_off);
        ushort* wq = (ushort*)(ws + wq_off);

        minmax_partial<<<dim3(1024), dim3(256), 0, stream>>>(x, n4, pmin, pmax);
        finalize_qp<<<dim3(1), dim3(64), 0, stream>>>(pmin, pmax, 1024, hdr);
        quant_x_kernel<<<dim3(2048), dim3(256), 0, stream>>>(x, xq, hdr, in_sizes[0] / 8);
        cvt_w_kernel<<<dim3(1024), dim3(256), 0, stream>>>(w, wq, in_sizes[1] / 8);

        const int nwg = (M / BM) * (N / BN);   // 2048
        gemm_bt<<<dim3(nwg), dim3(256), 0, stream>>>(xq, wq, bias, out, M, N, K);
    } else {
        int nb = 1024;
        size_t cap = ws_size / sizeof(float);
        if (cap < (size_t)(4096 + 1024)) {  // ultra-tiny ws guard
            long avail = (long)cap - 16;
            nb = avail > 2 ? (int)(avail / 2) : 1;
            pmin = hdr + 16;
            pmax = pmin + nb;
        }
        minmax_partial<<<dim3(nb), dim3(256), 0, stream>>>(x, n4, pmin, pmax);
        finalize_qp<<<dim3(1), dim3(64), 0, stream>>>(pmin, pmax, nb, hdr);
        dim3 grid(N / BN, M / BM);
        qgemm_fused<<<grid, dim3(256), 0, stream>>>(x, w, bias, hdr, out, M, N, K);
    }
}